// Round 11
// baseline (4972.195 us; speedup 1.0000x reference)
//
#include <hip/hip_runtime.h>
#include <hip/hip_bf16.h>

// Problem constants
#define BB 64
#define TT 512
#define DD 128
#define HH 256
#define G4 1024   // 4*H
#define CC 50

typedef __bf16 bf16x8 __attribute__((ext_vector_type(8)));
typedef float  f32x4  __attribute__((ext_vector_type(4)));
typedef _Float16 h16x2 __attribute__((ext_vector_type(2)));

#if defined(__has_builtin)
#if __has_builtin(__builtin_amdgcn_fdot2)
#define HAS_FDOT2 1
#endif
#endif

__device__ __forceinline__ float bl16(unsigned u) { return __uint_as_float(u << 16); }
__device__ __forceinline__ float bh16(unsigned u) { return __uint_as_float(u & 0xffff0000u); }

__device__ __forceinline__ float sigf(float x) {
    return 1.f / (1.f + __expf(-x));
}
__device__ __forceinline__ float tanh_s(float x) {
    float ax = fabsf(x);
    float e = __expf(-2.f * ax);
    float r = (1.f - e) / (1.f + e);
    return copysignf(r, x);
}

// anti-remat pins: the value's def becomes the asm, so the load can't be sunk
// into the loop. "v" = arch VGPR (<=256/thread), "a" = AGPR (unified file).
__device__ __forceinline__ void pinV(uint4& v) {
    asm volatile("" : "+v"(v.x), "+v"(v.y), "+v"(v.z), "+v"(v.w));
}
__device__ __forceinline__ void pinA(uint4& v) {
    asm volatile("" : "+a"(v.x), "+a"(v.y), "+a"(v.z), "+a"(v.w));
}

// 8-element f16 dot product chunk, f32 accumulate
__device__ __forceinline__ float dot8(float acc, uint4 w, uint4 h) {
#ifdef HAS_FDOT2
    acc = __builtin_amdgcn_fdot2(__builtin_bit_cast(h16x2, w.x),
                                 __builtin_bit_cast(h16x2, h.x), acc, false);
    acc = __builtin_amdgcn_fdot2(__builtin_bit_cast(h16x2, w.y),
                                 __builtin_bit_cast(h16x2, h.y), acc, false);
    acc = __builtin_amdgcn_fdot2(__builtin_bit_cast(h16x2, w.z),
                                 __builtin_bit_cast(h16x2, h.z), acc, false);
    acc = __builtin_amdgcn_fdot2(__builtin_bit_cast(h16x2, w.w),
                                 __builtin_bit_cast(h16x2, h.w), acc, false);
#else
    {
        h16x2 a = __builtin_bit_cast(h16x2, w.x), b = __builtin_bit_cast(h16x2, h.x);
        acc = fmaf((float)a.x, (float)b.x, acc); acc = fmaf((float)a.y, (float)b.y, acc);
        a = __builtin_bit_cast(h16x2, w.y); b = __builtin_bit_cast(h16x2, h.y);
        acc = fmaf((float)a.x, (float)b.x, acc); acc = fmaf((float)a.y, (float)b.y, acc);
        a = __builtin_bit_cast(h16x2, w.z); b = __builtin_bit_cast(h16x2, h.z);
        acc = fmaf((float)a.x, (float)b.x, acc); acc = fmaf((float)a.y, (float)b.y, acc);
        a = __builtin_bit_cast(h16x2, w.w); b = __builtin_bit_cast(h16x2, h.w);
        acc = fmaf((float)a.x, (float)b.x, acc); acc = fmaf((float)a.y, (float)b.y, acc);
    }
#endif
    return acc;
}

// ---------------------------------------------------------------------------
// Kernel 0: f32 -> bf16 conversion (8 elements/thread)
// ---------------------------------------------------------------------------
__global__ __launch_bounds__(256) void k_cvt(
    const float* __restrict__ src, __hip_bfloat16* __restrict__ dst, int n)
{
    int i = (blockIdx.x * 256 + threadIdx.x) * 8;
    if (i + 8 <= n) {
        float4 a = *(const float4*)(src + i);
        float4 b = *(const float4*)(src + i + 4);
        __hip_bfloat16 o[8];
        o[0] = __float2bfloat16(a.x); o[1] = __float2bfloat16(a.y);
        o[2] = __float2bfloat16(a.z); o[3] = __float2bfloat16(a.w);
        o[4] = __float2bfloat16(b.x); o[5] = __float2bfloat16(b.y);
        o[6] = __float2bfloat16(b.z); o[7] = __float2bfloat16(b.w);
        *(uint4*)(dst + i) = *(const uint4*)o;
    }
}

// f32 -> f16 variant
__global__ __launch_bounds__(256) void k_cvt16(
    const float* __restrict__ src, _Float16* __restrict__ dst, int n)
{
    int i = (blockIdx.x * 256 + threadIdx.x) * 8;
    if (i + 8 <= n) {
        float4 a = *(const float4*)(src + i);
        float4 b = *(const float4*)(src + i + 4);
        _Float16 o[8];
        o[0] = (_Float16)a.x; o[1] = (_Float16)a.y;
        o[2] = (_Float16)a.z; o[3] = (_Float16)a.w;
        o[4] = (_Float16)b.x; o[5] = (_Float16)b.y;
        o[6] = (_Float16)b.z; o[7] = (_Float16)b.w;
        *(uint4*)(dst + i) = *(const uint4*)o;
    }
}

// ---------------------------------------------------------------------------
// Kernel 0b: pack W_hh (f32 [1024][256]) -> f16 chunks for k_lstm v7.
// Thread j (of 256) owns rows {j, 256+j, 512+j, 768+j} (gates i,f,g,o).
// Wp[((dir*4 + r)*32 + kc)*256 + j] = 8 f16 of row r*256+j, k in [8kc,8kc+8)
// grid: 2 dir * 4 r * 32 kc = 256 blocks x 256 threads
// ---------------------------------------------------------------------------
__global__ __launch_bounds__(256) void k_pack(
    const float* __restrict__ Wf, const float* __restrict__ Wb,
    uint4* __restrict__ Wp)
{
    int blk = blockIdx.x;
    int kc = blk & 31;
    int r = (blk >> 5) & 3;
    int dir = blk >> 7;
    int j = threadIdx.x;
    int row = r * 256 + j;
    const float* src = (dir ? Wb : Wf) + (size_t)row * 256 + kc * 8;
    float4 a = *(const float4*)src;
    float4 b = *(const float4*)(src + 4);
    _Float16 o[8];
    o[0] = (_Float16)a.x; o[1] = (_Float16)a.y;
    o[2] = (_Float16)a.z; o[3] = (_Float16)a.w;
    o[4] = (_Float16)b.x; o[5] = (_Float16)b.y;
    o[6] = (_Float16)b.z; o[7] = (_Float16)b.w;
    Wp[((size_t)((dir * 4 + r) * 32 + kc)) * 256 + j] = *(const uint4*)o;
}

// ---------------------------------------------------------------------------
// Kernel 1: xg = emb[words] @ W_ih^T + b, LDS-staged GEMM (bf16 MFMA).
// 512 blocks x 256 threads. Block owns 64 bt-rows x ALL 2048 gates.
// ---------------------------------------------------------------------------
__global__ __launch_bounds__(256, 2) void k_xg(
    const int* __restrict__ words,
    const float* __restrict__ embf,           // f32 [50000][128]
    const __hip_bfloat16* __restrict__ Wih,   // bf16 [2048][128] (fwd|bwd)
    const float* __restrict__ bfv, const float* __restrict__ bbv,
    __hip_bfloat16* __restrict__ xg)
{
    __shared__ __align__(16) __hip_bfloat16 A[64][136];
    int tid = threadIdx.x;
    int bt0 = blockIdx.x * 64;

    {
        int r = tid >> 2;
        int c0 = (tid & 3) * 32;
        int word = words[bt0 + r];
        const float* src = embf + (size_t)word * DD + c0;
#pragma unroll
        for (int i = 0; i < 8; ++i) {
            float4 v = *(const float4*)(src + i * 4);
            __hip_bfloat16 o[4] = {__float2bfloat16(v.x), __float2bfloat16(v.y),
                                   __float2bfloat16(v.z), __float2bfloat16(v.w)};
            *(uint2*)&A[r][c0 + i * 4] = *(const uint2*)o;
        }
    }
    __syncthreads();

    int wave = tid >> 6, lane = tid & 63;
    int m = lane & 15, quad = lane >> 4;

    bf16x8 afr[4][4];
#pragma unroll
    for (int ms = 0; ms < 4; ++ms)
#pragma unroll
        for (int kf = 0; kf < 4; ++kf)
            afr[ms][kf] = *(const bf16x8*)&A[ms * 16 + m][quad * 8 + kf * 32];

#pragma unroll 1
    for (int i = 0; i < 32; ++i) {
        int nt = wave * 32 + i;
        int gate_g = nt * 16 + m;
        int dir = gate_g >> 10;
        int gate = gate_g & 1023;
        const __hip_bfloat16* brow = Wih + (size_t)gate_g * DD + quad * 8;
        bf16x8 bfr[4];
#pragma unroll
        for (int kf = 0; kf < 4; ++kf) bfr[kf] = *(const bf16x8*)(brow + kf * 32);
        float bv = dir ? bbv[gate] : bfv[gate];
        size_t dbase = (size_t)dir * (size_t)(BB * TT * G4);

#pragma unroll
        for (int ms = 0; ms < 4; ++ms) {
            f32x4 acc = {0.f, 0.f, 0.f, 0.f};
#pragma unroll
            for (int kf = 0; kf < 4; ++kf)
                acc = __builtin_amdgcn_mfma_f32_16x16x32_bf16(afr[ms][kf], bfr[kf], acc, 0, 0, 0);
#pragma unroll
            for (int r = 0; r < 4; ++r) {
                int btrow = bt0 + ms * 16 + quad * 4 + r;
                xg[dbase + (size_t)btrow * G4 + gate] = __float2bfloat16(acc[r] + bv);
            }
        }
    }
}

// ---------------------------------------------------------------------------
// Kernel 2: LSTM recurrence v7. 128 blocks x 256 threads (4 waves, 1/SIMD —
// the config where the compiler grants ~244 VGPRs). Thread j owns ALL 4 gate
// rows of cell j: gates stay in-thread, c in a register, ONE barrier/step.
// Residency per thread (128 chunk-slots total):
//   row i (32) pinned in arch VGPRs; rows f (32) + g kc0..11 pinned in AGPRs
//   (v_accvgpr_read on use, no memory traffic); g kc12..25 in LDS (56 KB);
//   g kc26..31 + row o (38 slots, 152 KB/block/step) streamed from L2.
// ---------------------------------------------------------------------------
__global__ __launch_bounds__(256, 1) void k_lstm(
    const __hip_bfloat16* __restrict__ xg,     // [2][B*T][1024] bf16
    const uint4* __restrict__ Wp,              // f16 packed [2][4][32][256]
    const int* __restrict__ seq_len,
    _Float16* __restrict__ hcat)               // [B*T][512] f16
{
    int b = blockIdx.x & 63;
    int dir = blockIdx.x >> 6;
    int j = threadIdx.x;   // 0..255

    __shared__ __align__(16) uint4 wg_lds[14 * 256];    // 57344 B (g, kc12..25)
    __shared__ __align__(16) _Float16 hbf[2][HH];       //  1024 B

    const uint4* Wd = Wp + (size_t)dir * 4 * 32 * 256;

    uint4 w0[32];   // row i -> arch VGPRs
#pragma unroll
    for (int kc = 0; kc < 32; ++kc) w0[kc] = Wd[(0 * 32 + kc) * 256 + j];
#pragma unroll
    for (int kc = 0; kc < 32; ++kc) pinV(w0[kc]);

    uint4 w1[32];   // row f -> AGPRs
#pragma unroll
    for (int kc = 0; kc < 32; ++kc) w1[kc] = Wd[(1 * 32 + kc) * 256 + j];
#pragma unroll
    for (int kc = 0; kc < 32; ++kc) pinA(w1[kc]);

    uint4 w2a[12];  // row g kc0..11 -> AGPRs
#pragma unroll
    for (int kc = 0; kc < 12; ++kc) w2a[kc] = Wd[(2 * 32 + kc) * 256 + j];
#pragma unroll
    for (int kc = 0; kc < 12; ++kc) pinA(w2a[kc]);

#pragma unroll
    for (int kc = 12; kc < 26; ++kc)
        wg_lds[(kc - 12) * 256 + j] = Wd[(2 * 32 + kc) * 256 + j];

    hbf[0][j] = (_Float16)0.f;
    float c = 0.f;
    int L = seq_len[b];
    const __hip_bfloat16* xgb = xg + (size_t)dir * (size_t)(BB * TT * G4)
                                   + (size_t)b * TT * G4;

    int tc = dir ? (L - 1) : 0;
    float xv0 = __bfloat162float(xgb[(size_t)tc * G4 + j]);
    float xv1 = __bfloat162float(xgb[(size_t)tc * G4 + 256 + j]);
    float xv2 = __bfloat162float(xgb[(size_t)tc * G4 + 512 + j]);
    float xv3 = __bfloat162float(xgb[(size_t)tc * G4 + 768 + j]);
    __syncthreads();

    for (int t = 0; t < TT; ++t) {
        int cur = t & 1, nxt = cur ^ 1;
        int tn = t + 1;
        int tcn = dir ? ((tn < L) ? (L - 1 - tn) : tn) : tn;
        bool pf = (tn < TT);
        __hip_bfloat16 p0, p1, p2, p3;
        if (pf) {
            p0 = xgb[(size_t)tcn * G4 + j];
            p1 = xgb[(size_t)tcn * G4 + 256 + j];
            p2 = xgb[(size_t)tcn * G4 + 512 + j];
            p3 = xgb[(size_t)tcn * G4 + 768 + j];
        }

        const uint4* hv4 = (const uint4*)&hbf[cur][0];
        float a0 = 0.f, a1 = 0.f, a2 = 0.f, a3 = 0.f;

        // issue first streamed window (row o kc0..7) before on-chip pass
        uint4 s0[8], s1[8];
#pragma unroll
        for (int i = 0; i < 8; ++i) s0[i] = Wd[(3 * 32 + i) * 256 + j];

        // on-chip pass: rows i, f, g(kc0..25)
#pragma unroll
        for (int kc = 0; kc < 32; ++kc) {
            uint4 hv = hv4[kc];
            a0 = dot8(a0, w0[kc], hv);
            a1 = dot8(a1, w1[kc], hv);
            if (kc < 12)      a2 = dot8(a2, w2a[kc], hv);
            else if (kc < 26) a2 = dot8(a2, wg_lds[(kc - 12) * 256 + j], hv);
        }

        // streamed row o: 32 slots, double-buffered by 8
#pragma unroll
        for (int g = 0; g < 4; ++g) {
            if (g < 3) {
#pragma unroll
                for (int i = 0; i < 8; ++i)
                    s1[i] = Wd[(3 * 32 + (g + 1) * 8 + i) * 256 + j];
            }
#pragma unroll
            for (int i = 0; i < 8; ++i)
                a3 = dot8(a3, s0[i], hv4[g * 8 + i]);
#pragma unroll
            for (int i = 0; i < 8; ++i) s0[i] = s1[i];
        }
        // streamed g tail kc26..31
        {
            uint4 sg[6];
#pragma unroll
            for (int i = 0; i < 6; ++i) sg[i] = Wd[(2 * 32 + 26 + i) * 256 + j];
#pragma unroll
            for (int i = 0; i < 6; ++i) a2 = dot8(a2, sg[i], hv4[26 + i]);
        }

        float gi = a0 + xv0, gf = a1 + xv1, gg_ = a2 + xv2, go = a3 + xv3;
        float i_ = sigf(gi), f_ = sigf(gf), G = tanh_s(gg_), o_ = sigf(go);
        c = f_ * c + i_ * G;
        float h = o_ * tanh_s(c);
        hbf[nxt][j] = (_Float16)h;
        hcat[((size_t)(b * TT + tc)) * (2 * HH) + dir * HH + j] = (_Float16)h;

        if (pf) {
            xv0 = __bfloat162float(p0); xv1 = __bfloat162float(p1);
            xv2 = __bfloat162float(p2); xv3 = __bfloat162float(p3);
        }
        tc = tcn;
        __syncthreads();
    }
}

// ---------------------------------------------------------------------------
// Kernel 3 (v2): feats = hcat @ fc_W^T + fc_b ; logits = log_softmax(feats).
// 512 blocks x 256 threads. fcW staged TRANSPOSED in LDS (conflict-free,
// coalesced); hcat row loads are wave-uniform (1 line/inst); softmax via
// wave shuffles. Kills the 64-line/inst fcW gather of v1.
// ---------------------------------------------------------------------------
__global__ __launch_bounds__(256) void k_fc(
    const _Float16* __restrict__ hcat,    // [32768][512] f16
    const _Float16* __restrict__ fcW16,   // [50][512] f16
    const float* __restrict__ fcb,
    float* __restrict__ logits)           // [32768][50]
{
    __shared__ __align__(16) uint4 fw[64 * 52];   // [kc][class], 53248 B
    int tid = threadIdx.x;
    const uint4* src = (const uint4*)fcW16;       // [50][64] chunks
    for (int idx = tid; idx < 50 * 64; idx += 256) {
        int cls = idx >> 6, kc = idx & 63;
        fw[kc * 52 + cls] = src[idx];
    }
    __syncthreads();

    int wave = tid >> 6, lane = tid & 63;
    int cl = (lane < CC) ? lane : (CC - 1);
    float bias = (lane < CC) ? fcb[lane] : 0.f;
    int r0 = blockIdx.x * 64 + wave * 16;

    for (int i = 0; i < 16; ++i) {
        int row = r0 + i;
        const uint4* hrow = (const uint4*)(hcat + (size_t)row * (2 * HH));
        float acc = bias;
#pragma unroll 16
        for (int kc = 0; kc < 64; ++kc) {
            uint4 hv = hrow[kc];                  // wave-uniform address
            acc = dot8(acc, fw[kc * 52 + cl], hv);
        }
        float v = (lane < CC) ? acc : -3.0e38f;
        float m = v;
#pragma unroll
        for (int o = 32; o > 0; o >>= 1) m = fmaxf(m, __shfl_xor(m, o));
        float e = (lane < CC) ? __expf(v - m) : 0.f;
        float s = e;
#pragma unroll
        for (int o = 32; o > 0; o >>= 1) s += __shfl_xor(s, o);
        float lns = __logf(s);
        if (lane < CC) logits[(size_t)row * CC + lane] = v - m - lns;
    }
}

// ---------------------------------------------------------------------------
// Kernel 4: CRF forward scan + gold score; per-batch loss -> loss_b[b]
// ---------------------------------------------------------------------------
__global__ __launch_bounds__(256) void k_crf(
    const float* __restrict__ logits,
    const int* __restrict__ target,
    const int* __restrict__ seq_len,
    const float* __restrict__ trans,
    const float* __restrict__ start_s,
    const float* __restrict__ end_s,
    float* __restrict__ loss_b)
{
    const float L2E = 1.4426950408889634f;
    const float LN2 = 0.6931471805599453f;
    int b = blockIdx.x;
    int tid = threadIdx.x;
    int q = tid >> 6;
    int j = tid & 63;
    bool act = (j < CC);
    int L = seq_len[b];
    const float* lg = logits + (size_t)b * TT * CC;

    __shared__ float alpha2[64];
    __shared__ float mpart[4][64];
    __shared__ float spart[4][64];
    __shared__ float red[256];
    __shared__ float nbuf[CC + 2];

    int i0 = q * 13;
    int icnt = min(13, CC - i0);
    float treg[13];
    if (act) {
#pragma unroll
        for (int s = 0; s < 13; ++s)
            if (s < icnt) treg[s] = L2E * trans[(i0 + s) * CC + j];
    }
    if (q == 0 && act) alpha2[j] = L2E * (lg[j] + start_s[j]);
    __syncthreads();

    float v[13];
    for (int t = 1; t < L; ++t) {
        float mq = -1e30f;
        if (act) {
#pragma unroll
            for (int s = 0; s < 13; ++s)
                if (s < icnt) { v[s] = alpha2[i0 + s] + treg[s]; mq = fmaxf(mq, v[s]); }
        }
        mpart[q][j] = mq;
        __syncthreads();
        float M = fmaxf(fmaxf(mpart[0][j], mpart[1][j]), fmaxf(mpart[2][j], mpart[3][j]));
        float sq = 0.f;
        if (act) {
#pragma unroll
            for (int s = 0; s < 13; ++s)
                if (s < icnt) sq += exp2f(v[s] - M);
        }
        spart[q][j] = sq;
        __syncthreads();
        if (q == 0 && act) {
            float S = spart[0][j] + spart[1][j] + spart[2][j] + spart[3][j];
            alpha2[j] = M + log2f(S) + L2E * lg[(size_t)t * CC + j];
        }
        __syncthreads();
    }

    if (q == 0 && act) nbuf[j] = alpha2[j] + L2E * end_s[j];

    float gp = 0.f;
    const int* tg = target + b * TT;
    for (int t = tid; t < TT; t += 256) {
        if (t < L) {
            int c = tg[t];
            gp += lg[(size_t)t * CC + c];
            if (t >= 1) gp += trans[tg[t - 1] * CC + c];
        }
    }
    red[tid] = gp;
    __syncthreads();

    if (tid == 0) {
        float m2 = -1e30f;
        for (int i = 0; i < CC; ++i) m2 = fmaxf(m2, nbuf[i]);
        float s2 = 0.f;
        for (int i = 0; i < CC; ++i) s2 += exp2f(nbuf[i] - m2);
        float norm_nat = (m2 + log2f(s2)) * LN2;
        float g = 0.f;
        for (int i = 0; i < 256; ++i) g += red[i];
        g += start_s[tg[0]] + end_s[tg[L - 1]];
        loss_b[b] = norm_nat - g;
    }
}

// Parallel final reduction (one wave)
__global__ void k_fin(const float* __restrict__ loss_b, float* __restrict__ out)
{
    int t = threadIdx.x;
    float v = loss_b[t];
#pragma unroll
    for (int o = 32; o > 0; o >>= 1) v += __shfl_down(v, o);
    if (t == 0) out[0] = v * (1.f / BB);
}

// ---------------------------------------------------------------------------
extern "C" void kernel_launch(void* const* d_in, const int* in_sizes, int n_in,
                              void* d_out, int out_size, void* d_ws, size_t ws_size,
                              hipStream_t stream)
{
    const int* words   = (const int*)d_in[0];
    const int* target  = (const int*)d_in[1];
    const int* seq_len = (const int*)d_in[2];
    const float* emb    = (const float*)d_in[3];
    const float* W_ih_f = (const float*)d_in[4];
    const float* W_hh_f = (const float*)d_in[5];
    const float* b_f    = (const float*)d_in[6];
    const float* W_ih_b = (const float*)d_in[7];
    const float* W_hh_b = (const float*)d_in[8];
    const float* b_b    = (const float*)d_in[9];
    const float* fc_W   = (const float*)d_in[10];
    const float* fc_b   = (const float*)d_in[11];
    const float* trans  = (const float*)d_in[12];
    const float* start_s= (const float*)d_in[13];
    const float* end_s  = (const float*)d_in[14];

    char* ws = (char*)d_ws;
    // workspace layout (bytes):
    //   xg     : 134217728                         @ 0
    //   hcat16 :  33554432  (f16 [32768][512])     @ 134217728
    //   logits :   6553600                         @ 167772160
    //     (Wp f16 lstm pack, 1 MB, overlaps logits: consumed by k_lstm
    //      BEFORE k_fc writes logits)
    //   loss_b :       256                         @ 174325760
    //   wihall :    524288  (bf16 [2048][128])     @ 174326016
    //   fcw16  :     51200  (f16 [50][512])        @ 174850304
    __hip_bfloat16* xg     = (__hip_bfloat16*)ws;
    _Float16*       hcat   = (_Float16*)(ws + 134217728);
    float*          logits = (float*)(ws + 167772160);
    uint4*          Wp     = (uint4*)(ws + 167772160);
    float*          loss_b = (float*)(ws + 174325760);
    __hip_bfloat16* wihall = (__hip_bfloat16*)(ws + 174326016);
    _Float16*       fcw16  = (_Float16*)(ws + 174850304);

    k_cvt  <<<64,  256, 0, stream>>>(W_ih_f, wihall,          131072);
    k_cvt  <<<64,  256, 0, stream>>>(W_ih_b, wihall + 131072, 131072);
    k_cvt16<<<13,  256, 0, stream>>>(fc_W,   fcw16,           25600);
    k_pack <<<256, 256, 0, stream>>>(W_hh_f, W_hh_b, Wp);

    k_xg  <<<512, 256, 0, stream>>>(words, emb, wihall, b_f, b_b, xg);
    k_lstm<<<128, 256, 0, stream>>>(xg, Wp, seq_len, hcat);
    k_fc  <<<512, 256, 0, stream>>>(hcat, fcw16, fc_b, logits);
    k_crf <<<64, 256, 0, stream>>>(logits, target, seq_len, trans, start_s, end_s, loss_b);
    k_fin <<<1, 64, 0, stream>>>(loss_b, (float*)d_out);
}